// Round 2
// baseline (3514.672 us; speedup 1.0000x reference)
//
#include <hip/hip_runtime.h>
#include <hip/hip_bf16.h>

#define NN 50000
#define NE 800000
#define FDIM 128
#define NBITS 64
#define NCLS 100
#define HD 300

__device__ __forceinline__ float us2f(unsigned short u) {
    union { unsigned int i; float f; } x; x.i = ((unsigned int)u) << 16; return x.f;
}
__device__ __forceinline__ unsigned short f2bf(float f) {
    union { float f; unsigned int i; } x; x.f = f;
    unsigned int i = x.i;
    i += 0x7fffu + ((i >> 16) & 1u);   // round-to-nearest-even
    return (unsigned short)(i >> 16);
}

template <bool BF>
__device__ __forceinline__ float ldv(const void* p, size_t i) {
    return BF ? us2f(((const unsigned short*)p)[i]) : ((const float*)p)[i];
}
template <bool BF>
__device__ __forceinline__ void stv(void* p, size_t i, float v) {
    if (BF) ((unsigned short*)p)[i] = f2bf(v);
    else    ((float*)p)[i] = v;
}

// ---------------- dtype detection ----------------
// Interpret first 4096 ushorts of features as bf16. Genuine bf16 N(0,1) data
// -> max|v| < 6. fp32 data read as bf16 -> mantissa fragments with random
// exponents >> 1e4 (or NaN) with probability ~1. flag=1 => bf16.
__global__ void __launch_bounds__(256) detect_kernel(const unsigned short* __restrict__ f,
                                                     int* __restrict__ flag) {
    __shared__ int bad;
    if (threadIdx.x == 0) bad = 0;
    __syncthreads();
    int b = 0;
    for (int i = threadIdx.x; i < 4096; i += 256) {
        float v = us2f(f[i]);
        if (!(fabsf(v) < 1e4f)) b = 1;   // catches NaN too
    }
    if (b) atomicOr(&bad, 1);
    __syncthreads();
    if (threadIdx.x == 0) flag[0] = bad ? 0 : 1;
}

// ---------------- degree count ----------------
__global__ void __launch_bounds__(256) count_kernel(const int* __restrict__ dst,
                                                    float* __restrict__ cnt) {
    int e = blockIdx.x * 256 + threadIdx.x;
    if (e < NE) unsafeAtomicAdd(&cnt[dst[e]], 1.0f);
}

// ---------------- scatter-add of messages ----------------
template <bool BF>
__device__ __forceinline__ void scatter_body(const void* xv, const int* src,
                                             const int* dst, float* agg) {
    int tid = blockIdx.x * 256 + threadIdx.x;
    int e = tid >> 5;
    if (e >= NE) return;
    int c = (tid & 31) * 4;
    int s = src[e], d = dst[e];
    float v0, v1, v2, v3;
    if (BF) {
        ushort4 u = *(const ushort4*)((const unsigned short*)xv + (size_t)s * FDIM + c);
        v0 = us2f(u.x); v1 = us2f(u.y); v2 = us2f(u.z); v3 = us2f(u.w);
    } else {
        float4 u = *(const float4*)((const float*)xv + (size_t)s * FDIM + c);
        v0 = u.x; v1 = u.y; v2 = u.z; v3 = u.w;
    }
    float* a = agg + (size_t)d * FDIM + c;
    unsafeAtomicAdd(a + 0, v0);
    unsafeAtomicAdd(a + 1, v1);
    unsafeAtomicAdd(a + 2, v2);
    unsafeAtomicAdd(a + 3, v3);
}

__global__ void __launch_bounds__(256) scatter_feat_kernel(const void* __restrict__ xv,
                                                           const int* __restrict__ src,
                                                           const int* __restrict__ dst,
                                                           float* __restrict__ agg,
                                                           const int* __restrict__ flag) {
    if (flag[0]) scatter_body<true>(xv, src, dst, agg);
    else         scatter_body<false>(xv, src, dst, agg);
}

__global__ void __launch_bounds__(256) scatter_f32_kernel(const float* __restrict__ x,
                                                          const int* __restrict__ src,
                                                          const int* __restrict__ dst,
                                                          float* __restrict__ agg) {
    scatter_body<false>(x, src, dst, agg);
}

// ---------------- fused SAGE linear: relu(mean@Wl + b + x@Wr) ----------------
// 8 nodes/block. hout may alias agg (in-place per-row): all global reads of
// agg happen before __syncthreads, writes after; blocks touch disjoint rows.
template <bool XBF, bool WBF>
__device__ __forceinline__ void sage_body(const float* agg, const float* cnt,
                                          const void* xv, const void* wl,
                                          const void* bl, const void* wr,
                                          float* hout) {
    __shared__ float ms[8][FDIM];
    __shared__ float xs[8][FDIM];
    int n0 = blockIdx.x * 8;
    int t = threadIdx.x;
    for (int idx = t; idx < 8 * FDIM; idx += 256) {
        int j = idx >> 7, k = idx & 127;
        int n = n0 + j;
        float c = cnt[n]; c = c > 1.f ? c : 1.f;
        ms[j][k] = agg[(size_t)n * FDIM + k] / c;
        xs[j][k] = ldv<XBF>(xv, (size_t)n * FDIM + k);
    }
    __syncthreads();
    int f = t & 127;
    int h = t >> 7;
    float acc[4] = {0.f, 0.f, 0.f, 0.f};
    for (int k = 0; k < FDIM; ++k) {
        float wlv = ldv<WBF>(wl, k * FDIM + f);
        float wrv = ldv<WBF>(wr, k * FDIM + f);
#pragma unroll
        for (int j = 0; j < 4; ++j) {
            int nn = h + j * 2;
            acc[j] += ms[nn][k] * wlv + xs[nn][k] * wrv;
        }
    }
    float bv = ldv<WBF>(bl, f);
#pragma unroll
    for (int j = 0; j < 4; ++j) {
        int nn = h + j * 2;
        float v = acc[j] + bv;
        hout[(size_t)(n0 + nn) * FDIM + f] = v > 0.f ? v : 0.f;
    }
}

__global__ void __launch_bounds__(256) sage1_kernel(const float* agg, const float* cnt,
                                                    const void* xv, const void* wl,
                                                    const void* bl, const void* wr,
                                                    float* hout, const int* flag) {
    if (flag[0]) sage_body<true, true>(agg, cnt, xv, wl, bl, wr, hout);
    else         sage_body<false, false>(agg, cnt, xv, wl, bl, wr, hout);
}

__global__ void __launch_bounds__(256) sage2_kernel(const float* agg, const float* cnt,
                                                    const float* x, const void* wl,
                                                    const void* bl, const void* wr,
                                                    float* hout, const int* flag) {
    if (flag[0]) sage_body<false, true>(agg, cnt, x, wl, bl, wr, hout);
    else         sage_body<false, false>(agg, cnt, x, wl, bl, wr, hout);
}

// ---------------- generic head GEMM: Y = act(X @ W + b) ----------------
// Y base is d_out; yoff is the section offset in ELEMENTS (dtype-agnostic).
template <int KDIM, bool TANH_IN, bool BF>
__device__ __forceinline__ void head_body(const float* X, const void* W, const void* B,
                                          void* Y, size_t yoff, int fout,
                                          const void* gamma, const void* beta,
                                          const void* rm, const void* rv,
                                          float* pre_ws, int mode) {
    __shared__ float xs[8][KDIM];
    int n0 = blockIdx.x * 8;
    int t = threadIdx.x;
    for (int idx = t; idx < 8 * KDIM; idx += 256) {
        int j = idx / KDIM, k = idx % KDIM;
        float v = X[(size_t)(n0 + j) * KDIM + k];
        xs[j][k] = TANH_IN ? tanhf(v) : v;
    }
    __syncthreads();
    for (int f = t; f < fout; f += 256) {
        float acc[8];
#pragma unroll
        for (int j = 0; j < 8; ++j) acc[j] = 0.f;
        for (int k = 0; k < KDIM; ++k) {
            float wv = ldv<BF>(W, (size_t)k * fout + f);
#pragma unroll
            for (int j = 0; j < 8; ++j) acc[j] += xs[j][k] * wv;
        }
        float bv = ldv<BF>(B, f);
        if (mode == 0) {
#pragma unroll
            for (int j = 0; j < 8; ++j)
                stv<BF>(Y, yoff + (size_t)(n0 + j) * fout + f, acc[j] + bv);
        } else {
            float g  = ldv<BF>(gamma, f);
            float be = ldv<BF>(beta, f);
            float m  = ldv<BF>(rm, f);
            float rs = rsqrtf(ldv<BF>(rv, f) + 1e-5f);
#pragma unroll
            for (int j = 0; j < 8; ++j) {
                float p = g * (acc[j] + bv - m) * rs + be;
                pre_ws[(size_t)(n0 + j) * fout + f] = p;
                stv<BF>(Y, yoff + (size_t)(n0 + j) * fout + f, tanhf(p));
            }
        }
    }
}

template <int KDIM, bool TANH_IN>
__global__ void __launch_bounds__(256) head_kernel(const float* X, const void* W,
                                                   const void* B, void* Y, size_t yoff,
                                                   int fout, const void* gamma,
                                                   const void* beta, const void* rm,
                                                   const void* rv, float* pre_ws,
                                                   int mode, const int* flag) {
    if (flag[0]) head_body<KDIM, TANH_IN, true>(X, W, B, Y, yoff, fout, gamma, beta, rm, rv, pre_ws, mode);
    else         head_body<KDIM, TANH_IN, false>(X, W, B, Y, yoff, fout, gamma, beta, rm, rv, pre_ws, mode);
}

// ---------------- true_lab: pre @ wtl + btl  (K=64, Fout=1) ----------------
template <bool BF>
__device__ __forceinline__ void tl_body(const float* pre, const void* wtl,
                                        const void* btl, void* y, size_t yoff) {
    int i = blockIdx.x * 256 + threadIdx.x;
    if (i >= NN) return;
    float s = ldv<BF>(btl, 0);
#pragma unroll 8
    for (int k = 0; k < NBITS; ++k) s += pre[(size_t)i * NBITS + k] * ldv<BF>(wtl, k);
    stv<BF>(y, yoff + i, s);
}

__global__ void __launch_bounds__(256) true_lab_kernel(const float* pre, const void* wtl,
                                                       const void* btl, void* y,
                                                       size_t yoff, const int* flag) {
    if (flag[0]) tl_body<true>(pre, wtl, btl, y, yoff);
    else         tl_body<false>(pre, wtl, btl, y, yoff);
}

extern "C" void kernel_launch(void* const* d_in, const int* in_sizes, int n_in,
                              void* d_out, int out_size, void* d_ws, size_t ws_size,
                              hipStream_t stream) {
    const void* feat = d_in[0];
    const int* edges = (const int*)d_in[1];
    const void* w1l = d_in[2];
    const void* b1l = d_in[3];
    const void* w1r = d_in[4];
    const void* w2l = d_in[5];
    const void* b2l = d_in[6];
    const void* w2r = d_in[7];
    const void* whd = d_in[8];
    const void* bhd = d_in[9];
    const void* wclas = d_in[10];
    const void* bclas = d_in[11];
    const void* wconv = d_in[12];
    const void* bconv = d_in[13];
    const void* gamma = d_in[14];
    const void* beta  = d_in[15];
    const void* rm  = d_in[16];
    const void* rv  = d_in[17];
    const void* wtl = d_in[18];
    const void* btl = d_in[19];
    const void* wcv = d_in[20];
    const void* bcv = d_in[21];

    // workspace (floats): flags[16] | cnt[50048] | buf1[6.4M] | buf2[6.4M] | pre[3.2M]
    // ~64.2 MB total. buf1 = agg1 then h1 (in-place); buf2 = agg2 then h2.
    float* ws   = (float*)d_ws;
    int*   flag = (int*)ws;
    float* cnt  = ws + 16;
    float* buf1 = ws + 16 + 50048;
    float* buf2 = buf1 + (size_t)NN * FDIM;
    float* pre  = buf2 + (size_t)NN * FDIM;

    const int* src = edges;
    const int* dst = edges + NE;

    hipMemsetAsync(ws, 0, (16 + 50048 + (size_t)NN * FDIM) * sizeof(float), stream);

    detect_kernel<<<1, 256, 0, stream>>>((const unsigned short*)feat, flag);
    count_kernel<<<(NE + 255) / 256, 256, 0, stream>>>(dst, cnt);

    // layer 1
    scatter_feat_kernel<<<(NE * 32) / 256, 256, 0, stream>>>(feat, src, dst, buf1, flag);
    sage1_kernel<<<NN / 8, 256, 0, stream>>>(buf1, cnt, feat, w1l, b1l, w1r, buf1, flag);

    // layer 2
    hipMemsetAsync(buf2, 0, (size_t)NN * FDIM * sizeof(float), stream);
    scatter_f32_kernel<<<(NE * 32) / 256, 256, 0, stream>>>(buf1, src, dst, buf2);
    sage2_kernel<<<NN / 8, 256, 0, stream>>>(buf2, cnt, buf1, w2l, b2l, w2r, buf2, flag);

    // output element offsets: logists | tanh_out | fea_lab | fea_convert | true_lab
    size_t o_log  = 0;
    size_t o_tanh = (size_t)NN * NCLS;
    size_t o_flab = o_tanh + (size_t)NN * NBITS;
    size_t o_fcv  = o_flab + (size_t)NN * HD;
    size_t o_tl   = o_fcv + (size_t)NN * NCLS;

    head_kernel<FDIM, false><<<NN / 8, 256, 0, stream>>>(
        buf2, whd, bhd, d_out, o_flab, HD,
        nullptr, nullptr, nullptr, nullptr, nullptr, 0, flag);
    head_kernel<FDIM, false><<<NN / 8, 256, 0, stream>>>(
        buf2, wclas, bclas, d_out, o_log, NCLS,
        nullptr, nullptr, nullptr, nullptr, nullptr, 0, flag);
    head_kernel<FDIM, false><<<NN / 8, 256, 0, stream>>>(
        buf2, wconv, bconv, d_out, o_tanh, NBITS,
        gamma, beta, rm, rv, pre, 1, flag);
    head_kernel<NBITS, true><<<NN / 8, 256, 0, stream>>>(
        pre, wcv, bcv, d_out, o_fcv, NCLS,
        nullptr, nullptr, nullptr, nullptr, nullptr, 0, flag);
    true_lab_kernel<<<(NN + 255) / 256, 256, 0, stream>>>(pre, wtl, btl, d_out, o_tl, flag);
}

// Round 3
// 1094.280 us; speedup vs baseline: 3.2119x; 3.2119x over previous
//
#include <hip/hip_runtime.h>
#include <hip/hip_bf16.h>

#define NN 50000
#define NE 800000
#define FDIM 128
#define NBITS 64
#define NCLS 100
#define HD 300

__device__ __forceinline__ float us2f(unsigned short u) {
    union { unsigned int i; float f; } x; x.i = ((unsigned int)u) << 16; return x.f;
}
__device__ __forceinline__ unsigned short f2bf(float f) {
    union { float f; unsigned int i; } x; x.f = f;
    unsigned int i = x.i;
    i += 0x7fffu + ((i >> 16) & 1u);   // round-to-nearest-even
    return (unsigned short)(i >> 16);
}

template <bool BF>
__device__ __forceinline__ float ldv(const void* p, size_t i) {
    return BF ? us2f(((const unsigned short*)p)[i]) : ((const float*)p)[i];
}
template <bool BF>
__device__ __forceinline__ void stv(void* p, size_t i, float v) {
    if (BF) ((unsigned short*)p)[i] = f2bf(v);
    else    ((float*)p)[i] = v;
}

// ---------------- dtype detection (flag=1 => bf16 buffers) ----------------
__global__ void __launch_bounds__(256) detect_kernel(const unsigned short* __restrict__ f,
                                                     int* __restrict__ flag) {
    __shared__ int bad;
    if (threadIdx.x == 0) bad = 0;
    __syncthreads();
    int b = 0;
    for (int i = threadIdx.x; i < 4096; i += 256) {
        float v = us2f(f[i]);
        if (!(fabsf(v) < 1e4f)) b = 1;   // catches NaN too
    }
    if (b) atomicOr(&bad, 1);
    __syncthreads();
    if (threadIdx.x == 0) flag[0] = bad ? 0 : 1;
}

// ---------------- CSR build ----------------
__global__ void __launch_bounds__(256) deg_kernel(const int* __restrict__ dst,
                                                  int* __restrict__ deg) {
    int e = blockIdx.x * 256 + threadIdx.x;
    if (e < NE) atomicAdd(&deg[dst[e]], 1);
}

// single-block hierarchical exclusive scan of deg[NN] -> rowptr[NN+1]
__global__ void __launch_bounds__(1024) scan_kernel(const int* __restrict__ deg,
                                                    int* __restrict__ rowptr) {
    __shared__ int wsum[16];
    __shared__ int carry_sh;
    int t = threadIdx.x;
    int lane = t & 63;
    int w = t >> 6;
    if (t == 0) carry_sh = 0;
    __syncthreads();
    for (int base = 0; base < NN; base += 1024) {
        int i = base + t;
        int v = (i < NN) ? deg[i] : 0;
        int x = v;
#pragma unroll
        for (int off = 1; off < 64; off <<= 1) {
            int u = __shfl_up(x, off);
            if (lane >= off) x += u;
        }
        if (lane == 63) wsum[w] = x;
        __syncthreads();
        if (w == 0) {
            int y = (lane < 16) ? wsum[lane] : 0;
#pragma unroll
            for (int off = 1; off < 16; off <<= 1) {
                int u = __shfl_up(y, off);
                if (lane >= off) y += u;
            }
            if (lane < 16) wsum[lane] = y;
        }
        __syncthreads();
        int woff = (w > 0) ? wsum[w - 1] : 0;
        int incl = x + woff;
        int carry = carry_sh;
        if (i < NN) rowptr[i] = carry + incl - v;   // exclusive
        __syncthreads();
        if (t == 1023) carry_sh = carry + incl;
        __syncthreads();
    }
    if (t == 0) rowptr[NN] = carry_sh;
}

__global__ void __launch_bounds__(256) fill_kernel(const int* __restrict__ src,
                                                   const int* __restrict__ dst,
                                                   const int* __restrict__ rowptr,
                                                   int* __restrict__ cursor,
                                                   int* __restrict__ col) {
    int e = blockIdx.x * 256 + threadIdx.x;
    if (e >= NE) return;
    int d = dst[e];
    int p = atomicAdd(&cursor[d], 1);
    col[rowptr[d] + p] = src[e];
}

// ---------------- gather aggregation: mean of neighbor rows ----------------
// one wave per node, 2 channels per lane (8B coalesced row reads)
template <bool BF>
__device__ __forceinline__ void agg_body(const void* xv, const int* rowptr,
                                         const int* col, float* aggm) {
    int node = blockIdx.x * 4 + (threadIdx.x >> 6);
    int lane = threadIdx.x & 63;
    int beg = rowptr[node], end = rowptr[node + 1];
    float a0 = 0.f, a1 = 0.f;
    for (int j = beg; j < end; ++j) {
        int nbr = col[j];
        if (BF) {
            ushort2 u = *(const ushort2*)((const unsigned short*)xv + (size_t)nbr * FDIM + lane * 2);
            a0 += us2f(u.x); a1 += us2f(u.y);
        } else {
            float2 u = *(const float2*)((const float*)xv + (size_t)nbr * FDIM + lane * 2);
            a0 += u.x; a1 += u.y;
        }
    }
    float inv = 1.f / fmaxf((float)(end - beg), 1.f);
    float2 o; o.x = a0 * inv; o.y = a1 * inv;
    *(float2*)(aggm + (size_t)node * FDIM + lane * 2) = o;
}

__global__ void __launch_bounds__(256) agg_feat_kernel(const void* __restrict__ xv,
                                                       const int* __restrict__ rowptr,
                                                       const int* __restrict__ col,
                                                       float* __restrict__ aggm,
                                                       const int* __restrict__ flag) {
    if (flag[0]) agg_body<true>(xv, rowptr, col, aggm);
    else         agg_body<false>(xv, rowptr, col, aggm);
}

__global__ void __launch_bounds__(256) agg_f32_kernel(const float* __restrict__ x,
                                                      const int* __restrict__ rowptr,
                                                      const int* __restrict__ col,
                                                      float* __restrict__ aggm) {
    agg_body<false>(x, rowptr, col, aggm);
}

// ---------------- fused SAGE linear: relu(mean@Wl + b + x@Wr) ----------------
// 8 nodes/block. hout may alias aggm (in-place per-row): all global reads
// happen before __syncthreads, writes after; blocks touch disjoint rows.
template <bool XBF, bool WBF>
__device__ __forceinline__ void sage_body(const float* aggm, const void* xv,
                                          const void* wl, const void* bl,
                                          const void* wr, float* hout) {
    __shared__ float ms[8][FDIM];
    __shared__ float xs[8][FDIM];
    int n0 = blockIdx.x * 8;
    int t = threadIdx.x;
    for (int idx = t; idx < 8 * FDIM; idx += 256) {
        int j = idx >> 7, k = idx & 127;
        int n = n0 + j;
        ms[j][k] = aggm[(size_t)n * FDIM + k];
        xs[j][k] = ldv<XBF>(xv, (size_t)n * FDIM + k);
    }
    __syncthreads();
    int f = t & 127;
    int h = t >> 7;
    float acc[4] = {0.f, 0.f, 0.f, 0.f};
    for (int k = 0; k < FDIM; ++k) {
        float wlv = ldv<WBF>(wl, k * FDIM + f);
        float wrv = ldv<WBF>(wr, k * FDIM + f);
#pragma unroll
        for (int j = 0; j < 4; ++j) {
            int nn = h + j * 2;
            acc[j] += ms[nn][k] * wlv + xs[nn][k] * wrv;
        }
    }
    float bv = ldv<WBF>(bl, f);
#pragma unroll
    for (int j = 0; j < 4; ++j) {
        int nn = h + j * 2;
        float v = acc[j] + bv;
        hout[(size_t)(n0 + nn) * FDIM + f] = v > 0.f ? v : 0.f;
    }
}

__global__ void __launch_bounds__(256) sage1_kernel(const float* aggm, const void* xv,
                                                    const void* wl, const void* bl,
                                                    const void* wr, float* hout,
                                                    const int* flag) {
    if (flag[0]) sage_body<true, true>(aggm, xv, wl, bl, wr, hout);
    else         sage_body<false, false>(aggm, xv, wl, bl, wr, hout);
}

__global__ void __launch_bounds__(256) sage2_kernel(const float* aggm, const float* x,
                                                    const void* wl, const void* bl,
                                                    const void* wr, float* hout,
                                                    const int* flag) {
    if (flag[0]) sage_body<false, true>(aggm, x, wl, bl, wr, hout);
    else         sage_body<false, false>(aggm, x, wl, bl, wr, hout);
}

// ---------------- generic head GEMM: Y = act(X @ W + b) ----------------
template <int KDIM, bool TANH_IN, bool BF>
__device__ __forceinline__ void head_body(const float* X, const void* W, const void* B,
                                          void* Y, size_t yoff, int fout,
                                          const void* gamma, const void* beta,
                                          const void* rm, const void* rv,
                                          float* pre_ws, int mode) {
    __shared__ float xs[8][KDIM];
    int n0 = blockIdx.x * 8;
    int t = threadIdx.x;
    for (int idx = t; idx < 8 * KDIM; idx += 256) {
        int j = idx / KDIM, k = idx % KDIM;
        float v = X[(size_t)(n0 + j) * KDIM + k];
        xs[j][k] = TANH_IN ? tanhf(v) : v;
    }
    __syncthreads();
    for (int f = t; f < fout; f += 256) {
        float acc[8];
#pragma unroll
        for (int j = 0; j < 8; ++j) acc[j] = 0.f;
        for (int k = 0; k < KDIM; ++k) {
            float wv = ldv<BF>(W, (size_t)k * fout + f);
#pragma unroll
            for (int j = 0; j < 8; ++j) acc[j] += xs[j][k] * wv;
        }
        float bv = ldv<BF>(B, f);
        if (mode == 0) {
#pragma unroll
            for (int j = 0; j < 8; ++j)
                stv<BF>(Y, yoff + (size_t)(n0 + j) * fout + f, acc[j] + bv);
        } else {
            float g  = ldv<BF>(gamma, f);
            float be = ldv<BF>(beta, f);
            float m  = ldv<BF>(rm, f);
            float rs = rsqrtf(ldv<BF>(rv, f) + 1e-5f);
#pragma unroll
            for (int j = 0; j < 8; ++j) {
                float p = g * (acc[j] + bv - m) * rs + be;
                pre_ws[(size_t)(n0 + j) * fout + f] = p;
                stv<BF>(Y, yoff + (size_t)(n0 + j) * fout + f, tanhf(p));
            }
        }
    }
}

template <int KDIM, bool TANH_IN>
__global__ void __launch_bounds__(256) head_kernel(const float* X, const void* W,
                                                   const void* B, void* Y, size_t yoff,
                                                   int fout, const void* gamma,
                                                   const void* beta, const void* rm,
                                                   const void* rv, float* pre_ws,
                                                   int mode, const int* flag) {
    if (flag[0]) head_body<KDIM, TANH_IN, true>(X, W, B, Y, yoff, fout, gamma, beta, rm, rv, pre_ws, mode);
    else         head_body<KDIM, TANH_IN, false>(X, W, B, Y, yoff, fout, gamma, beta, rm, rv, pre_ws, mode);
}

// ---------------- true_lab: pre @ wtl + btl  (K=64, Fout=1) ----------------
template <bool BF>
__device__ __forceinline__ void tl_body(const float* pre, const void* wtl,
                                        const void* btl, void* y, size_t yoff) {
    int i = blockIdx.x * 256 + threadIdx.x;
    if (i >= NN) return;
    float s = ldv<BF>(btl, 0);
#pragma unroll 8
    for (int k = 0; k < NBITS; ++k) s += pre[(size_t)i * NBITS + k] * ldv<BF>(wtl, k);
    stv<BF>(y, yoff + i, s);
}

__global__ void __launch_bounds__(256) true_lab_kernel(const float* pre, const void* wtl,
                                                       const void* btl, void* y,
                                                       size_t yoff, const int* flag) {
    if (flag[0]) tl_body<true>(pre, wtl, btl, y, yoff);
    else         tl_body<false>(pre, wtl, btl, y, yoff);
}

extern "C" void kernel_launch(void* const* d_in, const int* in_sizes, int n_in,
                              void* d_out, int out_size, void* d_ws, size_t ws_size,
                              hipStream_t stream) {
    const void* feat = d_in[0];
    const int* edges = (const int*)d_in[1];
    const void* w1l = d_in[2];
    const void* b1l = d_in[3];
    const void* w1r = d_in[4];
    const void* w2l = d_in[5];
    const void* b2l = d_in[6];
    const void* w2r = d_in[7];
    const void* whd = d_in[8];
    const void* bhd = d_in[9];
    const void* wclas = d_in[10];
    const void* bclas = d_in[11];
    const void* wconv = d_in[12];
    const void* bconv = d_in[13];
    const void* gamma = d_in[14];
    const void* beta  = d_in[15];
    const void* rm  = d_in[16];
    const void* rv  = d_in[17];
    const void* wtl = d_in[18];
    const void* btl = d_in[19];
    const void* wcv = d_in[20];
    const void* bcv = d_in[21];

    // workspace layout (all 16B-aligned element counts):
    //   int: flag[16] | deg[50000] | cursor[50000] | rowptr[50016] | col[800000]
    //   f32: buf1[NN*128] | buf2[NN*128]        (~55 MB total; pre overlays buf1)
    int* iw     = (int*)d_ws;
    int* flag   = iw;
    int* deg    = iw + 16;
    int* cursor = deg + NN;
    int* rowptr = cursor + NN;
    int* col    = rowptr + 50016;
    float* buf1 = (float*)(col + NE);
    float* buf2 = buf1 + (size_t)NN * FDIM;
    float* pre  = buf1;   // reuse: h1 dead after sage2

    const int* src = edges;
    const int* dst = edges + NE;

    // zero flag+deg+cursor (contiguous int region)
    hipMemsetAsync(iw, 0, (size_t)(16 + 2 * NN) * sizeof(int), stream);

    detect_kernel<<<1, 256, 0, stream>>>((const unsigned short*)feat, flag);

    // CSR build
    deg_kernel<<<(NE + 255) / 256, 256, 0, stream>>>(dst, deg);
    scan_kernel<<<1, 1024, 0, stream>>>(deg, rowptr);
    fill_kernel<<<(NE + 255) / 256, 256, 0, stream>>>(src, dst, rowptr, cursor, col);

    // layer 1: mean-gather into buf1, then h1 in place
    agg_feat_kernel<<<NN / 4, 256, 0, stream>>>(feat, rowptr, col, buf1, flag);
    sage1_kernel<<<NN / 8, 256, 0, stream>>>(buf1, feat, w1l, b1l, w1r, buf1, flag);

    // layer 2: mean-gather into buf2, then h2 in place
    agg_f32_kernel<<<NN / 4, 256, 0, stream>>>(buf1, rowptr, col, buf2);
    sage2_kernel<<<NN / 8, 256, 0, stream>>>(buf2, buf1, w2l, b2l, w2r, buf2, flag);

    // output element offsets: logists | tanh_out | fea_lab | fea_convert | true_lab
    size_t o_log  = 0;
    size_t o_tanh = (size_t)NN * NCLS;
    size_t o_flab = o_tanh + (size_t)NN * NBITS;
    size_t o_fcv  = o_flab + (size_t)NN * HD;
    size_t o_tl   = o_fcv + (size_t)NN * NCLS;

    head_kernel<FDIM, false><<<NN / 8, 256, 0, stream>>>(
        buf2, whd, bhd, d_out, o_flab, HD,
        nullptr, nullptr, nullptr, nullptr, nullptr, 0, flag);
    head_kernel<FDIM, false><<<NN / 8, 256, 0, stream>>>(
        buf2, wclas, bclas, d_out, o_log, NCLS,
        nullptr, nullptr, nullptr, nullptr, nullptr, 0, flag);
    head_kernel<FDIM, false><<<NN / 8, 256, 0, stream>>>(
        buf2, wconv, bconv, d_out, o_tanh, NBITS,
        gamma, beta, rm, rv, pre, 1, flag);
    head_kernel<NBITS, true><<<NN / 8, 256, 0, stream>>>(
        pre, wcv, bcv, d_out, o_fcv, NCLS,
        nullptr, nullptr, nullptr, nullptr, nullptr, 0, flag);
    true_lab_kernel<<<(NN + 255) / 256, 256, 0, stream>>>(pre, wtl, btl, d_out, o_tl, flag);
}

// Round 7
// 1004.557 us; speedup vs baseline: 3.4987x; 1.0893x over previous
//
#include <hip/hip_runtime.h>
#include <hip/hip_bf16.h>

#define NN 50000
#define NE 800000
#define FDIM 128
#define NBITS 64
#define NCLS 100
#define HD 300

__device__ __forceinline__ float us2f(unsigned short u) {
    union { unsigned int i; float f; } x; x.i = ((unsigned int)u) << 16; return x.f;
}
__device__ __forceinline__ unsigned short f2bf(float f) {
    union { float f; unsigned int i; } x; x.f = f;
    unsigned int i = x.i;
    i += 0x7fffu + ((i >> 16) & 1u);   // round-to-nearest-even
    return (unsigned short)(i >> 16);
}

template <bool BF>
__device__ __forceinline__ float ldv(const void* p, size_t i) {
    return BF ? us2f(((const unsigned short*)p)[i]) : ((const float*)p)[i];
}
template <bool BF>
__device__ __forceinline__ void stv(void* p, size_t i, float v) {
    if (BF) ((unsigned short*)p)[i] = f2bf(v);
    else    ((float*)p)[i] = v;
}

// ---------------- dtype detection (flag=1 => bf16 buffers) ----------------
__global__ void __launch_bounds__(256) detect_kernel(const unsigned short* __restrict__ f,
                                                     int* __restrict__ flag) {
    __shared__ int bad;
    if (threadIdx.x == 0) bad = 0;
    __syncthreads();
    int b = 0;
    for (int i = threadIdx.x; i < 4096; i += 256) {
        float v = us2f(f[i]);
        if (!(fabsf(v) < 1e4f)) b = 1;   // catches NaN too
    }
    if (b) atomicOr(&bad, 1);
    __syncthreads();
    if (threadIdx.x == 0) flag[0] = bad ? 0 : 1;
}

// ---------------- CSR build ----------------
__global__ void __launch_bounds__(256) deg_kernel(const int* __restrict__ dst,
                                                  int* __restrict__ deg) {
    int e = blockIdx.x * 256 + threadIdx.x;
    if (e < NE) atomicAdd(&deg[dst[e]], 1);
}

// single-block hierarchical exclusive scan of deg[NN] -> rowptr[NN+1]
__global__ void __launch_bounds__(1024) scan_kernel(const int* __restrict__ deg,
                                                    int* __restrict__ rowptr) {
    __shared__ int wsum[16];
    __shared__ int carry_sh;
    int t = threadIdx.x;
    int lane = t & 63;
    int w = t >> 6;
    if (t == 0) carry_sh = 0;
    __syncthreads();
    for (int base = 0; base < NN; base += 1024) {
        int i = base + t;
        int v = (i < NN) ? deg[i] : 0;
        int x = v;
#pragma unroll
        for (int off = 1; off < 64; off <<= 1) {
            int u = __shfl_up(x, off);
            if (lane >= off) x += u;
        }
        if (lane == 63) wsum[w] = x;
        __syncthreads();
        if (w == 0) {
            int y = (lane < 16) ? wsum[lane] : 0;
#pragma unroll
            for (int off = 1; off < 16; off <<= 1) {
                int u = __shfl_up(y, off);
                if (lane >= off) y += u;
            }
            if (lane < 16) wsum[lane] = y;
        }
        __syncthreads();
        int woff = (w > 0) ? wsum[w - 1] : 0;
        int incl = x + woff;
        int carry = carry_sh;
        if (i < NN) rowptr[i] = carry + incl - v;   // exclusive
        __syncthreads();
        if (t == 1023) carry_sh = carry + incl;
        __syncthreads();
    }
    if (t == 0) rowptr[NN] = carry_sh;
}

__global__ void __launch_bounds__(256) fill_kernel(const int* __restrict__ src,
                                                   const int* __restrict__ dst,
                                                   const int* __restrict__ rowptr,
                                                   int* __restrict__ cursor,
                                                   int* __restrict__ col) {
    int e = blockIdx.x * 256 + threadIdx.x;
    if (e >= NE) return;
    int d = dst[e];
    int p = atomicAdd(&cursor[d], 1);
    col[rowptr[d] + p] = src[e];
}

// ---------------- gather aggregation: mean of neighbor rows ----------------
// one wave per node, 2 channels per lane (8B coalesced row reads)
template <bool BF>
__device__ __forceinline__ void agg_body(const void* xv, const int* rowptr,
                                         const int* col, float* aggm) {
    int node = blockIdx.x * 4 + (threadIdx.x >> 6);
    int lane = threadIdx.x & 63;
    int beg = rowptr[node], end = rowptr[node + 1];
    float a0 = 0.f, a1 = 0.f;
    for (int j = beg; j < end; ++j) {
        int nbr = col[j];
        if (BF) {
            ushort2 u = *(const ushort2*)((const unsigned short*)xv + (size_t)nbr * FDIM + lane * 2);
            a0 += us2f(u.x); a1 += us2f(u.y);
        } else {
            float2 u = *(const float2*)((const float*)xv + (size_t)nbr * FDIM + lane * 2);
            a0 += u.x; a1 += u.y;
        }
    }
    float inv = 1.f / fmaxf((float)(end - beg), 1.f);
    float2 o; o.x = a0 * inv; o.y = a1 * inv;
    *(float2*)(aggm + (size_t)node * FDIM + lane * 2) = o;
}

__global__ void __launch_bounds__(256) agg_feat_kernel(const void* __restrict__ xv,
                                                       const int* __restrict__ rowptr,
                                                       const int* __restrict__ col,
                                                       float* __restrict__ aggm,
                                                       const int* __restrict__ flag) {
    if (flag[0]) agg_body<true>(xv, rowptr, col, aggm);
    else         agg_body<false>(xv, rowptr, col, aggm);
}

__global__ void __launch_bounds__(256) agg_f32_kernel(const float* __restrict__ x,
                                                      const int* __restrict__ rowptr,
                                                      const int* __restrict__ col,
                                                      float* __restrict__ aggm) {
    agg_body<false>(x, rowptr, col, aggm);
}

// ---------------- fused SAGE linear: relu(mean@Wl + b + x@Wr) ----------------
// 8 nodes/block. hout may alias aggm (in-place per-row): all global reads
// happen before __syncthreads, writes after; blocks touch disjoint rows.
template <bool XBF, bool WBF>
__device__ __forceinline__ void sage_body(const float* aggm, const void* xv,
                                          const void* wl, const void* bl,
                                          const void* wr, float* hout) {
    __shared__ float ms[8][FDIM];
    __shared__ float xs[8][FDIM];
    int n0 = blockIdx.x * 8;
    int t = threadIdx.x;
    for (int idx = t; idx < 8 * FDIM; idx += 256) {
        int j = idx >> 7, k = idx & 127;
        int n = n0 + j;
        ms[j][k] = aggm[(size_t)n * FDIM + k];
        xs[j][k] = ldv<XBF>(xv, (size_t)n * FDIM + k);
    }
    __syncthreads();
    int f = t & 127;
    int h = t >> 7;
    float acc[4] = {0.f, 0.f, 0.f, 0.f};
    for (int k = 0; k < FDIM; ++k) {
        float wlv = ldv<WBF>(wl, k * FDIM + f);
        float wrv = ldv<WBF>(wr, k * FDIM + f);
#pragma unroll
        for (int j = 0; j < 4; ++j) {
            int nn = h + j * 2;
            acc[j] += ms[nn][k] * wlv + xs[nn][k] * wrv;
        }
    }
    float bv = ldv<WBF>(bl, f);
#pragma unroll
    for (int j = 0; j < 4; ++j) {
        int nn = h + j * 2;
        float v = acc[j] + bv;
        hout[(size_t)(n0 + nn) * FDIM + f] = v > 0.f ? v : 0.f;
    }
}

__global__ void __launch_bounds__(256) sage1_kernel(const float* aggm, const void* xv,
                                                    const void* wl, const void* bl,
                                                    const void* wr, float* hout,
                                                    const int* flag) {
    if (flag[0]) sage_body<true, true>(aggm, xv, wl, bl, wr, hout);
    else         sage_body<false, false>(aggm, xv, wl, bl, wr, hout);
}

__global__ void __launch_bounds__(256) sage2_kernel(const float* aggm, const float* x,
                                                    const void* wl, const void* bl,
                                                    const void* wr, float* hout,
                                                    const int* flag) {
    if (flag[0]) sage_body<false, true>(aggm, x, wl, bl, wr, hout);
    else         sage_body<false, false>(aggm, x, wl, bl, wr, hout);
}

// ---------------- generic head GEMM: Y = act(X @ W + b) ----------------
// ROUND-7 DELTA (the ONLY change vs the round-3 pass): 16 rows/block (was 8)
// to halve redundant W streaming. Grid NN/16.
template <int KDIM, bool TANH_IN, bool BF>
__device__ __forceinline__ void head_body(const float* X, const void* W, const void* B,
                                          void* Y, size_t yoff, int fout,
                                          const void* gamma, const void* beta,
                                          const void* rm, const void* rv,
                                          float* pre_ws, int mode) {
    __shared__ float xs[16][KDIM];
    int n0 = blockIdx.x * 16;
    int t = threadIdx.x;
    for (int idx = t; idx < 16 * KDIM; idx += 256) {
        int j = idx / KDIM, k = idx % KDIM;
        float v = X[(size_t)(n0 + j) * KDIM + k];
        xs[j][k] = TANH_IN ? tanhf(v) : v;
    }
    __syncthreads();
    for (int f = t; f < fout; f += 256) {
        float acc[16];
#pragma unroll
        for (int j = 0; j < 16; ++j) acc[j] = 0.f;
        for (int k = 0; k < KDIM; ++k) {
            float wv = ldv<BF>(W, (size_t)k * fout + f);
#pragma unroll
            for (int j = 0; j < 16; ++j) acc[j] += xs[j][k] * wv;
        }
        float bv = ldv<BF>(B, f);
        if (mode == 0) {
#pragma unroll
            for (int j = 0; j < 16; ++j)
                stv<BF>(Y, yoff + (size_t)(n0 + j) * fout + f, acc[j] + bv);
        } else {
            float g  = ldv<BF>(gamma, f);
            float be = ldv<BF>(beta, f);
            float m  = ldv<BF>(rm, f);
            float rs = rsqrtf(ldv<BF>(rv, f) + 1e-5f);
#pragma unroll
            for (int j = 0; j < 16; ++j) {
                float p = g * (acc[j] + bv - m) * rs + be;
                pre_ws[(size_t)(n0 + j) * fout + f] = p;
                stv<BF>(Y, yoff + (size_t)(n0 + j) * fout + f, tanhf(p));
            }
        }
    }
}

template <int KDIM, bool TANH_IN>
__global__ void __launch_bounds__(256) head_kernel(const float* X, const void* W,
                                                   const void* B, void* Y, size_t yoff,
                                                   int fout, const void* gamma,
                                                   const void* beta, const void* rm,
                                                   const void* rv, float* pre_ws,
                                                   int mode, const int* flag) {
    if (flag[0]) head_body<KDIM, TANH_IN, true>(X, W, B, Y, yoff, fout, gamma, beta, rm, rv, pre_ws, mode);
    else         head_body<KDIM, TANH_IN, false>(X, W, B, Y, yoff, fout, gamma, beta, rm, rv, pre_ws, mode);
}

// ---------------- true_lab: pre @ wtl + btl  (K=64, Fout=1) ----------------
template <bool BF>
__device__ __forceinline__ void tl_body(const float* pre, const void* wtl,
                                        const void* btl, void* y, size_t yoff) {
    int i = blockIdx.x * 256 + threadIdx.x;
    if (i >= NN) return;
    float s = ldv<BF>(btl, 0);
#pragma unroll 8
    for (int k = 0; k < NBITS; ++k) s += pre[(size_t)i * NBITS + k] * ldv<BF>(wtl, k);
    stv<BF>(y, yoff + i, s);
}

__global__ void __launch_bounds__(256) true_lab_kernel(const float* pre, const void* wtl,
                                                       const void* btl, void* y,
                                                       size_t yoff, const int* flag) {
    if (flag[0]) tl_body<true>(pre, wtl, btl, y, yoff);
    else         tl_body<false>(pre, wtl, btl, y, yoff);
}

extern "C" void kernel_launch(void* const* d_in, const int* in_sizes, int n_in,
                              void* d_out, int out_size, void* d_ws, size_t ws_size,
                              hipStream_t stream) {
    const void* feat = d_in[0];
    const int* edges = (const int*)d_in[1];
    const void* w1l = d_in[2];
    const void* b1l = d_in[3];
    const void* w1r = d_in[4];
    const void* w2l = d_in[5];
    const void* b2l = d_in[6];
    const void* w2r = d_in[7];
    const void* whd = d_in[8];
    const void* bhd = d_in[9];
    const void* wclas = d_in[10];
    const void* bclas = d_in[11];
    const void* wconv = d_in[12];
    const void* bconv = d_in[13];
    const void* gamma = d_in[14];
    const void* beta  = d_in[15];
    const void* rm  = d_in[16];
    const void* rv  = d_in[17];
    const void* wtl = d_in[18];
    const void* btl = d_in[19];
    const void* wcv = d_in[20];
    const void* bcv = d_in[21];

    // workspace layout (identical to the round-3 pass):
    //   int: flag[16] | deg[50000] | cursor[50000] | rowptr[50016] | col[800000]
    //   f32: buf1[NN*128] | buf2[NN*128]        (~55 MB total; pre overlays buf1)
    int* iw     = (int*)d_ws;
    int* flag   = iw;
    int* deg    = iw + 16;
    int* cursor = deg + NN;
    int* rowptr = cursor + NN;
    int* col    = rowptr + 50016;
    float* buf1 = (float*)(col + NE);
    float* buf2 = buf1 + (size_t)NN * FDIM;
    float* pre  = buf1;   // reuse: h1 dead after sage2

    const int* src = edges;
    const int* dst = edges + NE;

    // zero flag+deg+cursor (contiguous int region)
    hipMemsetAsync(iw, 0, (size_t)(16 + 2 * NN) * sizeof(int), stream);

    detect_kernel<<<1, 256, 0, stream>>>((const unsigned short*)feat, flag);

    // CSR build
    deg_kernel<<<(NE + 255) / 256, 256, 0, stream>>>(dst, deg);
    scan_kernel<<<1, 1024, 0, stream>>>(deg, rowptr);
    fill_kernel<<<(NE + 255) / 256, 256, 0, stream>>>(src, dst, rowptr, cursor, col);

    // layer 1: mean-gather into buf1, then h1 in place
    agg_feat_kernel<<<NN / 4, 256, 0, stream>>>(feat, rowptr, col, buf1, flag);
    sage1_kernel<<<NN / 8, 256, 0, stream>>>(buf1, feat, w1l, b1l, w1r, buf1, flag);

    // layer 2: mean-gather into buf2, then h2 in place
    agg_f32_kernel<<<NN / 4, 256, 0, stream>>>(buf1, rowptr, col, buf2);
    sage2_kernel<<<NN / 8, 256, 0, stream>>>(buf2, buf1, w2l, b2l, w2r, buf2, flag);

    // output element offsets: logists | tanh_out | fea_lab | fea_convert | true_lab
    size_t o_log  = 0;
    size_t o_tanh = (size_t)NN * NCLS;
    size_t o_flab = o_tanh + (size_t)NN * NBITS;
    size_t o_fcv  = o_flab + (size_t)NN * HD;
    size_t o_tl   = o_fcv + (size_t)NN * NCLS;

    head_kernel<FDIM, false><<<NN / 16, 256, 0, stream>>>(
        buf2, whd, bhd, d_out, o_flab, HD,
        nullptr, nullptr, nullptr, nullptr, nullptr, 0, flag);
    head_kernel<FDIM, false><<<NN / 16, 256, 0, stream>>>(
        buf2, wclas, bclas, d_out, o_log, NCLS,
        nullptr, nullptr, nullptr, nullptr, nullptr, 0, flag);
    head_kernel<FDIM, false><<<NN / 16, 256, 0, stream>>>(
        buf2, wconv, bconv, d_out, o_tanh, NBITS,
        gamma, beta, rm, rv, pre, 1, flag);
    head_kernel<NBITS, true><<<NN / 16, 256, 0, stream>>>(
        pre, wcv, bcv, d_out, o_fcv, NCLS,
        nullptr, nullptr, nullptr, nullptr, nullptr, 0, flag);
    true_lab_kernel<<<(NN + 255) / 256, 256, 0, stream>>>(pre, wtl, btl, d_out, o_tl, flag);
}